// Round 7
// baseline (600.712 us; speedup 1.0000x reference)
//
#include <hip/hip_runtime.h>
#include <hip/hip_bf16.h>
#include <stdint.h>

// Fused causal MHA, B=256,T=128,H=8,D=256,C=256. One block per (h,b).
// Round 7: fragment-order ws (X and W stored as lane-linear 1KB MFMA
// fragments). A/B operands load straight from L2/L3 into registers via
// coalesced global_load_dwordx4 -> no W LDS ring, no global_load_lds,
// 6 barriers per block. LDS only for Q/K/VT/P/O transposes (160KB).

#define TT 128
#define CC 256
#define DD 256

typedef __attribute__((ext_vector_type(8))) short short8;
typedef __attribute__((ext_vector_type(4))) float f32x4;

// LDS regions
#define R1 0         // Q [128t][512B swz]  -> VT [256d][256B swz]
#define R2 65536     // K [128s][512B swz]  -> O  [128t][512B swz]
#define R3 131072    // redM/redS (2KB head) -> P [128t][256B swz]
#define LDS_SIZE 163840

// ws map (needs >= 20054016 B)
#define WS_X    0u                      // 256 b x 64KB   (A-frag order)
#define WS_WQ   16777216u               // 8 h x 128KB    (B-frag order)
#define WS_WK   (WS_WQ + 1048576u)
#define WS_WV   (WS_WQ + 2097152u)
#define WS_WP   (WS_WQ + 3145728u)      // 128KB

#define LGKM0()  asm volatile("s_waitcnt lgkmcnt(0)" ::: "memory")
#define BAR()    do { asm volatile("" ::: "memory"); __builtin_amdgcn_s_barrier(); asm volatile("" ::: "memory"); } while (0)
#define PRIO1()  __builtin_amdgcn_s_setprio(1)
#define PRIO0()  __builtin_amdgcn_s_setprio(0)

__device__ __forceinline__ unsigned short f2bf(float x) {
    union { float f; unsigned u; } v; v.f = x;
    unsigned r = v.u + 0x7FFFu + ((v.u >> 16) & 1u);
    return (unsigned short)(r >> 16);
}
__device__ __forceinline__ unsigned pk2(float a, float b) {
    return (unsigned)f2bf(a) | ((unsigned)f2bf(b) << 16);
}

// ---------------- convert: fp32 -> bf16 fragment-order, via LDS transpose ----------------
// grid: 256 blocks for X (one per b) + 25 blocks for W (Wq h0..7, Wk, Wv, Wp).
__global__ __launch_bounds__(256) void convert_pre(
    const float* __restrict__ x,
    const float* __restrict__ Wq, const float* __restrict__ Wk,
    const float* __restrict__ Wv, const float* __restrict__ Wp,
    char* __restrict__ ws)
{
    extern __shared__ char clds[];
    const int tid = threadIdx.x;
    const int bid = blockIdx.x;
    const float* src; char* dst; int rows;
    if (bid < 256) {
        src = x + (size_t)bid * 32768;
        dst = ws + WS_X + (size_t)bid * 65536;
        rows = 128;
    } else {
        int id = bid - 256;
        if (id < 8)       { src = Wq + (size_t)id * 65536;      dst = ws + WS_WQ + (size_t)id * 131072; }
        else if (id < 16) { src = Wk + (size_t)(id-8) * 65536;  dst = ws + WS_WK + (size_t)(id-8) * 131072; }
        else if (id < 24) { src = Wv + (size_t)(id-16) * 65536; dst = ws + WS_WV + (size_t)(id-16) * 131072; }
        else              { src = Wp;                           dst = ws + WS_WP; }
        rows = 256;
    }
    // stage 1: coalesced read, bf16-pack, swizzled rows into LDS
    const int nf4 = rows * 64;
    for (int i = tid; i < nf4; i += 256) {
        float4 v = ((const float4*)src)[i];
        int row = i >> 6, c4 = i & 63;
        uint2 u; u.x = pk2(v.x, v.y); u.y = pk2(v.z, v.w);
        *(uint2*)(clds + row * 512 + ((c4 * 8) ^ ((row & 7) << 4))) = u;
    }
    __syncthreads();
    // stage 2: emit fragment-order 16B chunks (coalesced writes)
    const int nch = rows * 32;
    for (int i = tid; i < nch; i += 256) {
        int l = i & 63, ks = (i >> 6) & 7, g = i >> 9;
        int r = g * 16 + (l & 15);
        int boff = ks * 64 + (l >> 4) * 16;
        uint4 q = *(const uint4*)(clds + r * 512 + (boff ^ ((r & 7) << 4)));
        ((uint4*)dst)[i] = q;
    }
}

// ---------------- main fused kernel ----------------
__global__ __launch_bounds__(512, 2) void mha_fused(
    const char* __restrict__ ws,
    const float* __restrict__ bq, const float* __restrict__ bk,
    const float* __restrict__ bv, const float* __restrict__ bp,
    float* __restrict__ out)
{
    extern __shared__ char lds[];
    const int tid = threadIdx.x;
    const int w  = tid >> 6, l = tid & 63;
    const int lg = l >> 4, lr = l & 15;
    const int mq = w & 3, nh = w >> 2;        // 4 M-waves x 2 N-waves
    const int bid = blockIdx.x;
    const int h = bid >> 8, b = bid & 255;
    const int t0 = mq * 32 + lr, t1 = t0 + 16;

    const char* Xf  = ws + WS_X  + (size_t)b * 65536;
    const char* WqB = ws + WS_WQ + (size_t)h * 131072;
    const char* WkB = ws + WS_WK + (size_t)h * 131072;
    const char* WvB = ws + WS_WV + (size_t)h * 131072;
    const char* WpB = ws + WS_WP;

    // X A-fragments (rowgroups mq*2, mq*2+1)
    short8 xf[2][8];
    #pragma unroll
    for (int mt = 0; mt < 2; ++mt)
        #pragma unroll
        for (int ks = 0; ks < 8; ++ks)
            xf[mt][ks] = *(const short8*)(Xf + (((mq*2 + mt)*8 + ks) << 10) + l*16);

    // ---- P0: Q-proj -> R1, K-proj -> R2 ----
    #pragma unroll
    for (int m2 = 0; m2 < 2; ++m2) {
        const char* WB = m2 ? WkB : WqB;
        const float* bpt = m2 ? (bk + h*256) : (bq + h*256);
        char* dst = lds + (m2 ? R2 : R1);
        const float scl = m2 ? 1.0f : 0.0625f;
        #pragma unroll
        for (int dc = 0; dc < 4; ++dc) {
            const int ga = nh*8 + dc*2;
            short8 bf[2][8];
            #pragma unroll
            for (int nt = 0; nt < 2; ++nt)
                #pragma unroll
                for (int ks = 0; ks < 8; ++ks)
                    bf[nt][ks] = *(const short8*)(WB + (((ga+nt)*8 + ks) << 10) + l*16);
            f32x4 acc[2][2];
            #pragma unroll
            for (int i = 0; i < 2; ++i)
                #pragma unroll
                for (int j = 0; j < 2; ++j) acc[i][j] = f32x4{0.f,0.f,0.f,0.f};
            PRIO1();
            #pragma unroll
            for (int ks = 0; ks < 8; ++ks)
                #pragma unroll
                for (int mt = 0; mt < 2; ++mt)
                    #pragma unroll
                    for (int nt = 0; nt < 2; ++nt)
                        acc[mt][nt] = __builtin_amdgcn_mfma_f32_16x16x32_bf16(xf[mt][ks], bf[nt][ks], acc[mt][nt], 0, 0, 0);
            PRIO0();
            #pragma unroll
            for (int nt = 0; nt < 2; ++nt) {
                int d = (ga+nt)*16 + lr;
                float bias = bpt[d];
                #pragma unroll
                for (int mt = 0; mt < 2; ++mt)
                    #pragma unroll
                    for (int r = 0; r < 4; ++r) {
                        int t = mq*32 + mt*16 + lg*4 + r;
                        *(unsigned short*)(dst + t*512 + ((d*2) ^ ((t&7)<<4)))
                            = f2bf((acc[mt][nt][r] + bias) * scl);
                    }
            }
        }
    }
    LGKM0(); BAR();

    // ---- P2: V-proj into vreg (global B), then S-stream, then redM ----
    uint2 vreg[4][2][2];
    #pragma unroll
    for (int dc = 0; dc < 4; ++dc) {
        const int ga = nh*8 + dc*2;
        short8 bf[2][8];
        #pragma unroll
        for (int nt = 0; nt < 2; ++nt)
            #pragma unroll
            for (int ks = 0; ks < 8; ++ks)
                bf[nt][ks] = *(const short8*)(WvB + (((ga+nt)*8 + ks) << 10) + l*16);
        f32x4 acc[2][2];
        #pragma unroll
        for (int i = 0; i < 2; ++i)
            #pragma unroll
            for (int j = 0; j < 2; ++j) acc[i][j] = f32x4{0.f,0.f,0.f,0.f};
        PRIO1();
        #pragma unroll
        for (int ks = 0; ks < 8; ++ks)
            #pragma unroll
            for (int mt = 0; mt < 2; ++mt)
                #pragma unroll
                for (int nt = 0; nt < 2; ++nt)
                    acc[mt][nt] = __builtin_amdgcn_mfma_f32_16x16x32_bf16(xf[mt][ks], bf[nt][ks], acc[mt][nt], 0, 0, 0);
        PRIO0();
        #pragma unroll
        for (int nt = 0; nt < 2; ++nt) {
            int d = (ga+nt)*16 + lr;
            float bias = bv[h*256 + d];
            #pragma unroll
            for (int mt = 0; mt < 2; ++mt) {
                vreg[dc][mt][nt].x = pk2(acc[mt][nt][0] + bias, acc[mt][nt][1] + bias);
                vreg[dc][mt][nt].y = pk2(acc[mt][nt][2] + bias, acc[mt][nt][3] + bias);
            }
        }
    }
    // S = Q K^T (streamed from LDS)
    f32x4 sacc[2][4];
    #pragma unroll
    for (int i = 0; i < 2; ++i)
        #pragma unroll
        for (int j = 0; j < 4; ++j) sacc[i][j] = f32x4{0.f,0.f,0.f,0.f};
    #pragma unroll
    for (int ks = 0; ks < 8; ++ks) {
        int cb = ks*64 + lg*16;
        short8 qa0 = *(const short8*)(lds + R1 + t0*512 + (cb ^ ((t0&7)<<4)));
        short8 qa1 = *(const short8*)(lds + R1 + t1*512 + (cb ^ ((t1&7)<<4)));
        short8 kb[4];
        #pragma unroll
        for (int nt = 0; nt < 4; ++nt) {
            int srow = nh*64 + nt*16 + lr;
            kb[nt] = *(const short8*)(lds + R2 + srow*512 + (cb ^ ((srow&7)<<4)));
        }
        PRIO1();
        #pragma unroll
        for (int nt = 0; nt < 4; ++nt) {
            sacc[0][nt] = __builtin_amdgcn_mfma_f32_16x16x32_bf16(qa0, kb[nt], sacc[0][nt], 0, 0, 0);
            sacc[1][nt] = __builtin_amdgcn_mfma_f32_16x16x32_bf16(qa1, kb[nt], sacc[1][nt], 0, 0, 0);
        }
        PRIO0();
    }
    // causal mask + row max
    float* redM = (float*)(lds + R3);
    float* redS = redM + 256;
    {
        float rmax[2][4];
        #pragma unroll
        for (int mt = 0; mt < 2; ++mt)
            #pragma unroll
            for (int r = 0; r < 4; ++r) {
                int t = mq*32 + mt*16 + lg*4 + r;
                float m = -1e30f;
                #pragma unroll
                for (int nt = 0; nt < 4; ++nt) {
                    int s = nh*64 + nt*16 + lr;
                    if (s > t) sacc[mt][nt][r] = -1e30f;
                    m = fmaxf(m, sacc[mt][nt][r]);
                }
                m = fmaxf(m, __shfl_xor(m, 1));
                m = fmaxf(m, __shfl_xor(m, 2));
                m = fmaxf(m, __shfl_xor(m, 4));
                m = fmaxf(m, __shfl_xor(m, 8));
                rmax[mt][r] = m;
            }
        if (lr == 0) {
            #pragma unroll
            for (int mt = 0; mt < 2; ++mt)
                #pragma unroll
                for (int r = 0; r < 4; ++r)
                    redM[nh*128 + mq*32 + mt*16 + lg*4 + r] = rmax[mt][r];
        }
    }
    LGKM0(); BAR();

    // ---- P3: VT write (R1, Q dead) + softmax mid (exp, sums) ----
    #pragma unroll
    for (int dc = 0; dc < 4; ++dc)
        #pragma unroll
        for (int nt = 0; nt < 2; ++nt) {
            int d = (nh*8 + dc*2 + nt)*16 + lr;
            #pragma unroll
            for (int mt = 0; mt < 2; ++mt) {
                int s0 = mq*32 + mt*16 + lg*4;
                *(uint2*)(lds + R1 + d*256 + ((s0*2) ^ ((d&7)<<4))) = vreg[dc][mt][nt];
            }
        }
    {
        float rsum[2][4];
        #pragma unroll
        for (int mt = 0; mt < 2; ++mt)
            #pragma unroll
            for (int r = 0; r < 4; ++r) {
                int t = mq*32 + mt*16 + lg*4 + r;
                float m = fmaxf(redM[t], redM[128 + t]);
                float ssum = 0.f;
                #pragma unroll
                for (int nt = 0; nt < 4; ++nt) {
                    float p = __expf(sacc[mt][nt][r] - m);
                    sacc[mt][nt][r] = p;
                    ssum += p;
                }
                ssum += __shfl_xor(ssum, 1);
                ssum += __shfl_xor(ssum, 2);
                ssum += __shfl_xor(ssum, 4);
                ssum += __shfl_xor(ssum, 8);
                rsum[mt][r] = ssum;
            }
        if (lr == 0) {
            #pragma unroll
            for (int mt = 0; mt < 2; ++mt)
                #pragma unroll
                for (int r = 0; r < 4; ++r)
                    redS[nh*128 + mq*32 + mt*16 + lg*4 + r] = rsum[mt][r];
        }
    }
    LGKM0(); BAR();

    // ---- P4: read inv (tiny) ----
    float inv[2][4];
    #pragma unroll
    for (int mt = 0; mt < 2; ++mt)
        #pragma unroll
        for (int r = 0; r < 4; ++r) {
            int t = mq*32 + mt*16 + lg*4 + r;
            inv[mt][r] = 1.0f / (redS[t] + redS[128 + t]);
        }
    LGKM0(); BAR();

    // ---- P5: P write (R3, red dead) ----
    #pragma unroll
    for (int mt = 0; mt < 2; ++mt)
        #pragma unroll
        for (int r = 0; r < 4; ++r) {
            int t = mq*32 + mt*16 + lg*4 + r;
            #pragma unroll
            for (int nt = 0; nt < 4; ++nt) {
                int s = nh*64 + nt*16 + lr;
                *(unsigned short*)(lds + R3 + t*256 + ((s*2) ^ ((t&7)<<4)))
                    = f2bf(sacc[mt][nt][r] * inv[mt][r]);
            }
        }
    LGKM0(); BAR();

    // ---- P6: PV (P x VT) -> O write (R2, K dead) ----
    f32x4 oacc[2][8];
    #pragma unroll
    for (int i = 0; i < 2; ++i)
        #pragma unroll
        for (int j = 0; j < 8; ++j) oacc[i][j] = f32x4{0.f,0.f,0.f,0.f};
    #pragma unroll
    for (int ks = 0; ks < 4; ++ks) {
        int sb = ks*64 + lg*16;
        short8 pa0 = *(const short8*)(lds + R3 + t0*256 + (sb ^ ((t0&7)<<4)));
        short8 pa1 = *(const short8*)(lds + R3 + t1*256 + (sb ^ ((t1&7)<<4)));
        PRIO1();
        #pragma unroll
        for (int nd = 0; nd < 8; ++nd) {
            int d = nh*128 + nd*16 + lr;
            short8 vb = *(const short8*)(lds + R1 + d*256 + (sb ^ ((d&7)<<4)));
            oacc[0][nd] = __builtin_amdgcn_mfma_f32_16x16x32_bf16(pa0, vb, oacc[0][nd], 0, 0, 0);
            oacc[1][nd] = __builtin_amdgcn_mfma_f32_16x16x32_bf16(pa1, vb, oacc[1][nd], 0, 0, 0);
        }
        PRIO0();
    }
    #pragma unroll
    for (int mt = 0; mt < 2; ++mt)
        #pragma unroll
        for (int nd = 0; nd < 8; ++nd)
            #pragma unroll
            for (int r = 0; r < 4; ++r) {
                int t = mq*32 + mt*16 + lg*4 + r;
                int e = nh*128 + nd*16 + lr;
                *(unsigned short*)(lds + R2 + t*512 + ((e*2) ^ ((t&7)<<4)))
                    = f2bf(oacc[mt][nd][r]);
            }
    LGKM0(); BAR();

    // ---- P7: OUT = O * Wp^T + bp (B-frags from global) ----
    short8 of[2][8];
    #pragma unroll
    for (int mt = 0; mt < 2; ++mt) {
        int t = mq*32 + mt*16 + lr;
        #pragma unroll
        for (int ks = 0; ks < 8; ++ks)
            of[mt][ks] = *(const short8*)(lds + R2 + t*512 + ((ks*64 + lg*16) ^ ((t&7)<<4)));
    }
    #pragma unroll
    for (int ec = 0; ec < 4; ++ec) {
        const int ga = nh*8 + ec*2;
        short8 bf[2][8];
        #pragma unroll
        for (int nt = 0; nt < 2; ++nt)
            #pragma unroll
            for (int ks = 0; ks < 8; ++ks)
                bf[nt][ks] = *(const short8*)(WpB + (((ga+nt)*8 + ks) << 10) + l*16);
        f32x4 acc[2][2];
        #pragma unroll
        for (int i = 0; i < 2; ++i)
            #pragma unroll
            for (int j = 0; j < 2; ++j) acc[i][j] = f32x4{0.f,0.f,0.f,0.f};
        PRIO1();
        #pragma unroll
        for (int ks = 0; ks < 8; ++ks)
            #pragma unroll
            for (int mt = 0; mt < 2; ++mt)
                #pragma unroll
                for (int nt = 0; nt < 2; ++nt)
                    acc[mt][nt] = __builtin_amdgcn_mfma_f32_16x16x32_bf16(of[mt][ks], bf[nt][ks], acc[mt][nt], 0, 0, 0);
        PRIO0();
        #pragma unroll
        for (int nt = 0; nt < 2; ++nt) {
            int e = (ga+nt)*16 + lr;
            float bias = bp[e];
            #pragma unroll
            for (int mt = 0; mt < 2; ++mt)
                #pragma unroll
                for (int r = 0; r < 4; ++r) {
                    int t = mq*32 + mt*16 + lg*4 + r;
                    out[((size_t)bid * TT + t) * DD + e] = acc[mt][nt][r] + bias;
                }
        }
    }
}

extern "C" void kernel_launch(void* const* d_in, const int* in_sizes, int n_in,
                              void* d_out, int out_size, void* d_ws, size_t ws_size,
                              hipStream_t stream) {
    (void)in_sizes; (void)n_in; (void)out_size; (void)ws_size; // needs ws_size >= 20054016
    const float* x  = (const float*)d_in[0];
    const float* Wq = (const float*)d_in[1];
    const float* bq = (const float*)d_in[2];
    const float* Wk = (const float*)d_in[3];
    const float* bk = (const float*)d_in[4];
    const float* Wv = (const float*)d_in[5];
    const float* bv = (const float*)d_in[6];
    const float* Wp = (const float*)d_in[7];
    const float* bp = (const float*)d_in[8];
    char* ws = (char*)d_ws;

    hipFuncSetAttribute((const void*)convert_pre,
                        hipFuncAttributeMaxDynamicSharedMemorySize, 131072);
    convert_pre<<<dim3(281), dim3(256), 131072, stream>>>(x, Wq, Wk, Wv, Wp, ws);

    hipFuncSetAttribute((const void*)mha_fused,
                        hipFuncAttributeMaxDynamicSharedMemorySize, LDS_SIZE);
    mha_fused<<<dim3(2048), dim3(512), LDS_SIZE, stream>>>(
        ws, bq, bk, bv, bp, (float*)d_out);
}

// Round 8
// 389.241 us; speedup vs baseline: 1.5433x; 1.5433x over previous
//
#include <hip/hip_runtime.h>
#include <hip/hip_bf16.h>
#include <stdint.h>

// Fused causal MHA, B=256,T=128,H=8,D=256,C=256. One block per (h,b).
// Round 8: algebraic fold. S = X M X^T + v + u + cqk (M = Wq^T Wk /16),
// OUT = P (WM X^T)^T + bb (WM = Wp Wv, bb = bp + Wp bv). 3 proj-equiv per
// block instead of 5. All global operands in MFMA fragment order in ws;
// X's B-frags == A-frags (row x k), so S/H B-operands stream from L2.
// 5 barriers/block. Per-phase acc tiles capped at 32 VGPR (anti-spill).

#define TT 128

typedef __attribute__((ext_vector_type(8))) short short8;
typedef __attribute__((ext_vector_type(4))) float f32x4;

// ---- ws map (total 18948128 B < proven-available 20054016) ----
#define WS_X    0u                       // 256 b x 64KB  X A/B-frags
#define WS_M    16777216u                // 8 h x 128KB   M^T-layout B-frags (scaled 1/16)
#define WS_WM   17825792u                // 8 h x 128KB   WM A-frags
#define WS_WB   18874368u                // 8 h x 8KB     [w2;w1] B-frags (rows 0,1), zero-filled
#define WS_BB   18939904u                // 8 h x 1KB     bb fp32
#define WS_CQ   18948096u                // 8 x 4B        cqk fp32

// ---- LDS map (101376 B) ----
#define R_T1   0        // T1 [128t][512B swz] -> H [256e][256B swz]
#define R_P    65536    // P  [128t][256B swz]
#define R_UV   98304    // v[128] f32 | u[128] f32
#define R_RED  99328    // redM[256] | redS[256]
#define LDS_SIZE 101376

#define LGKM0()  asm volatile("s_waitcnt lgkmcnt(0)" ::: "memory")
#define BAR()    do { asm volatile("" ::: "memory"); __builtin_amdgcn_s_barrier(); asm volatile("" ::: "memory"); } while (0)
#define PRIO1()  __builtin_amdgcn_s_setprio(1)
#define PRIO0()  __builtin_amdgcn_s_setprio(0)

__device__ __forceinline__ unsigned short f2bf(float x) {
    union { float f; unsigned u; } v; v.f = x;
    unsigned r = v.u + 0x7FFFu + ((v.u >> 16) & 1u);
    return (unsigned short)(r >> 16);
}
__device__ __forceinline__ unsigned pk2(float a, float b) {
    return (unsigned)f2bf(a) | ((unsigned)f2bf(b) << 16);
}

// =============== convert / fold kernel =====================================
// blocks 0..255   : X[b] fp32 -> bf16 frag order (via LDS transpose)
// blocks 256..383 : M strips   (h = (bid-256)>>4, c'-strip = (bid-256)&15)
// blocks 384..511 : WM strips  (h = (bid-384)>>4, e-strip)
// block  512      : wbias frags + bb + cqk
__global__ __launch_bounds__(256) void convert_pre(
    const float* __restrict__ x,
    const float* __restrict__ Wq, const float* __restrict__ bq,
    const float* __restrict__ Wk, const float* __restrict__ bk,
    const float* __restrict__ Wv, const float* __restrict__ bv,
    const float* __restrict__ Wp, const float* __restrict__ bp,
    char* __restrict__ ws)
{
    extern __shared__ char clds[];
    const int tid = threadIdx.x;
    const int bid = blockIdx.x;

    if (bid < 256) {
        // ---- X -> frag order ----
        const float* src = x + (size_t)bid * 32768;
        char* dst = ws + WS_X + (size_t)bid * 65536;
        for (int i = tid; i < 8192; i += 256) {
            float4 v = ((const float4*)src)[i];
            int row = i >> 6, c4 = i & 63;
            uint2 u; u.x = pk2(v.x, v.y); u.y = pk2(v.z, v.w);
            *(uint2*)(clds + row * 512 + ((c4 * 8) ^ ((row & 7) << 4))) = u;
        }
        __syncthreads();
        for (int i = tid; i < 4096; i += 256) {
            int l = i & 63, ks = (i >> 6) & 7, g = i >> 9;
            int r = g * 16 + (l & 15);
            int boff = ks * 64 + (l >> 4) * 16;
            uint4 q = *(const uint4*)(clds + r * 512 + (boff ^ ((r & 7) << 4)));
            ((uint4*)dst)[i] = q;
        }
        return;
    }
    if (bid < 384) {
        // ---- M[c,c'] = sum_d Wq[d,c] Wk[d,c'], store as B-frag of N[c',c]=M[c,c']/16 ----
        int id = bid - 256, h = id >> 4, st = id & 15;
        float* wkL = (float*)clds;                    // [256 d][16 cc]
        for (int i = tid; i < 4096; i += 256) {
            int d = i >> 4, cc = i & 15;
            wkL[i] = Wk[(size_t)h * 65536 + d * 256 + st * 16 + cc];
        }
        __syncthreads();
        const int c = tid;
        float acc[16];
        #pragma unroll
        for (int j = 0; j < 16; ++j) acc[j] = 0.f;
        #pragma unroll 4
        for (int d = 0; d < 256; ++d) {
            float a = Wq[(size_t)h * 65536 + d * 256 + c];
            #pragma unroll
            for (int j = 0; j < 16; ++j) acc[j] += a * wkL[d * 16 + j];
        }
        char* base = ws + WS_M + (size_t)h * 131072;
        int ks = c >> 5, lgp = (c >> 3) & 3, jb = c & 7;
        #pragma unroll
        for (int j = 0; j < 16; ++j) {
            int cp = st * 16 + j;                     // row (n) = c'
            *(unsigned short*)(base + (((st * 8 + ks)) << 10)
                + ((cp & 15) + 16 * lgp) * 16 + jb * 2) = f2bf(acc[j] * 0.0625f);
        }
        return;
    }
    if (bid < 512) {
        // ---- WM[e,c] = sum_d Wp[e,d] Wv_h[d,c], store as A-frag (row e, col c) ----
        int id = bid - 384, h = id >> 4, st = id & 15;
        float* wpL = (float*)clds;                    // [16 e][257 d]
        for (int i = tid; i < 4096; i += 256) {
            int e = i >> 8, d = i & 255;
            wpL[e * 257 + d] = Wp[(size_t)(st * 16 + e) * 256 + d];
        }
        __syncthreads();
        const int c = tid;
        float acc[16];
        #pragma unroll
        for (int j = 0; j < 16; ++j) acc[j] = 0.f;
        #pragma unroll 4
        for (int d = 0; d < 256; ++d) {
            float wv = Wv[(size_t)h * 65536 + d * 256 + c];
            #pragma unroll
            for (int j = 0; j < 16; ++j) acc[j] += wv * wpL[j * 257 + d];
        }
        char* base = ws + WS_WM + (size_t)h * 131072;
        int ks = c >> 5, lgp = (c >> 3) & 3, jb = c & 7;
        #pragma unroll
        for (int j = 0; j < 16; ++j) {
            *(unsigned short*)(base + (((st * 8 + ks)) << 10)
                + (j + 16 * lgp) * 16 + jb * 2) = f2bf(acc[j]);
        }
        return;
    }
    // ---- block 512: wbias frags (rows 0=w2, 1=w1), bb, cqk ----
    {
        uint4 z = {0u,0u,0u,0u};
        for (int i = tid; i < 4096; i += 256) ((uint4*)(ws + WS_WB))[i] = z;
        __syncthreads();
        const int c = tid;
        int ks = c >> 5, lgp = (c >> 3) & 3, jb = c & 7;
        for (int h = 0; h < 8; ++h) {
            float s1 = 0.f, s2 = 0.f;
            for (int d = 0; d < 256; ++d) {
                s1 += Wk[(size_t)h * 65536 + d * 256 + c] * bq[h * 256 + d];
                s2 += Wq[(size_t)h * 65536 + d * 256 + c] * bk[h * 256 + d];
            }
            char* base = ws + WS_WB + h * 8192 + ks * 1024;
            *(unsigned short*)(base + (0 + 16 * lgp) * 16 + jb * 2) = f2bf(s2 * 0.0625f); // row0: w2 -> v
            *(unsigned short*)(base + (1 + 16 * lgp) * 16 + jb * 2) = f2bf(s1 * 0.0625f); // row1: w1 -> u
        }
        // bb[h][e] = bp[e] + sum_d bv_h[d] Wp[e,d]
        const int e = tid;
        float s[8];
        #pragma unroll
        for (int h = 0; h < 8; ++h) s[h] = 0.f;
        for (int d = 0; d < 256; ++d) {
            float wp = Wp[(size_t)e * 256 + d];
            #pragma unroll
            for (int h = 0; h < 8; ++h) s[h] += bv[h * 256 + d] * wp;
        }
        #pragma unroll
        for (int h = 0; h < 8; ++h)
            *(float*)(ws + WS_BB + h * 1024 + e * 4) = bp[e] + s[h];
        if (tid < 8) {
            float cq = 0.f;
            for (int d = 0; d < 256; ++d) cq += bq[tid * 256 + d] * bk[tid * 256 + d];
            *(float*)(ws + WS_CQ + tid * 4) = cq * 0.0625f;
        }
    }
}

// =============== main fused kernel =========================================
__global__ __launch_bounds__(512, 2) void mha_fused(
    const char* __restrict__ ws, float* __restrict__ out)
{
    extern __shared__ char lds[];
    const int tid = threadIdx.x;
    const int w  = tid >> 6, l = tid & 63;
    const int lg = l >> 4, lr = l & 15;
    const int mq = w & 3, nh = w >> 2;      // 4 M-waves x 2 N-waves
    const int bid = blockIdx.x;
    const int h = bid >> 8, b = bid & 255;

    const char* Xf  = ws + WS_X  + (size_t)b * 65536;
    const char* Mh  = ws + WS_M  + (size_t)h * 131072;
    const char* WMh = ws + WS_WM + (size_t)h * 131072;
    const char* WBh = ws + WS_WB + (size_t)h * 8192;

    // X A-frags (row-groups mq*2+mt)
    short8 xf[2][8];
    #pragma unroll
    for (int mt = 0; mt < 2; ++mt)
        #pragma unroll
        for (int ks = 0; ks < 8; ++ks)
            xf[mt][ks] = *(const short8*)(Xf + (((mq*2 + mt)*8 + ks) << 10) + l*16);

    // ---- Ph0a: [v|u] = X * [w2;w1]^T ----
    {
        f32x4 vacc[2] = {f32x4{0.f,0.f,0.f,0.f}, f32x4{0.f,0.f,0.f,0.f}};
        #pragma unroll
        for (int ks = 0; ks < 8; ++ks) {
            short8 wb = *(const short8*)(WBh + (ks << 10) + l*16);
            vacc[0] = __builtin_amdgcn_mfma_f32_16x16x32_bf16(xf[0][ks], wb, vacc[0], 0, 0, 0);
            vacc[1] = __builtin_amdgcn_mfma_f32_16x16x32_bf16(xf[1][ks], wb, vacc[1], 0, 0, 0);
        }
        if (nh == 0 && lr < 2) {
            #pragma unroll
            for (int mt = 0; mt < 2; ++mt)
                #pragma unroll
                for (int r = 0; r < 4; ++r) {
                    int t = mq*32 + mt*16 + lg*4 + r;
                    *(float*)(lds + R_UV + lr*512 + t*4) = vacc[mt][r];
                }
        }
    }

    // ---- Ph0b: T1 = X * N  (N = M^T-layout, scaled 1/16) -> LDS C-layout ----
    #pragma unroll
    for (int p = 0; p < 2; ++p) {
        const int ga = nh*8 + p*4;
        f32x4 acc[2][4];
        #pragma unroll
        for (int i = 0; i < 2; ++i)
            #pragma unroll
            for (int j = 0; j < 4; ++j) acc[i][j] = f32x4{0.f,0.f,0.f,0.f};
        #pragma unroll
        for (int ks = 0; ks < 8; ++ks) {
            short8 nb[4];
            #pragma unroll
            for (int nt = 0; nt < 4; ++nt)
                nb[nt] = *(const short8*)(Mh + (((ga+nt)*8 + ks) << 10) + l*16);
            PRIO1();
            #pragma unroll
            for (int mt = 0; mt < 2; ++mt)
                #pragma unroll
                for (int nt = 0; nt < 4; ++nt)
                    acc[mt][nt] = __builtin_amdgcn_mfma_f32_16x16x32_bf16(xf[mt][ks], nb[nt], acc[mt][nt], 0, 0, 0);
            PRIO0();
        }
        #pragma unroll
        for (int mt = 0; mt < 2; ++mt)
            #pragma unroll
            for (int nt = 0; nt < 4; ++nt)
                #pragma unroll
                for (int r = 0; r < 4; ++r) {
                    int t = mq*32 + mt*16 + lg*4 + r;
                    int cp = (ga+nt)*16 + lr;
                    *(unsigned short*)(lds + R_T1 + t*512 + ((cp*2) ^ ((t&7)<<4)))
                        = f2bf(acc[mt][nt][r]);
                }
    }
    LGKM0(); BAR();

    // ---- Ph1: S = T1 * X^T + v + u + cqk ; mask ; softmax ; P -> LDS ----
    f32x4 sacc[2][4];
    #pragma unroll
    for (int i = 0; i < 2; ++i)
        #pragma unroll
        for (int j = 0; j < 4; ++j) sacc[i][j] = f32x4{0.f,0.f,0.f,0.f};
    #pragma unroll
    for (int ks = 0; ks < 8; ++ks) {
        short8 ta[2];
        #pragma unroll
        for (int mt = 0; mt < 2; ++mt) {
            int t2 = mq*32 + mt*16 + lr;
            ta[mt] = *(const short8*)(lds + R_T1 + t2*512 + ((ks*64 + lg*16) ^ ((t2&7)<<4)));
        }
        short8 sb[4];
        #pragma unroll
        for (int nt = 0; nt < 4; ++nt)
            sb[nt] = *(const short8*)(Xf + (((nh*4+nt)*8 + ks) << 10) + l*16);
        PRIO1();
        #pragma unroll
        for (int mt = 0; mt < 2; ++mt)
            #pragma unroll
            for (int nt = 0; nt < 4; ++nt)
                sacc[mt][nt] = __builtin_amdgcn_mfma_f32_16x16x32_bf16(ta[mt], sb[nt], sacc[mt][nt], 0, 0, 0);
        PRIO0();
    }
    {
        const float cq = *(const float*)(ws + WS_CQ + h*4);
        float uu[4];
        #pragma unroll
        for (int nt = 0; nt < 4; ++nt)
            uu[nt] = *(const float*)(lds + R_UV + 512 + (nh*64 + nt*16 + lr)*4);
        float* redM = (float*)(lds + R_RED);
        float* redS = redM + 256;
        float rmax[2][4];
        #pragma unroll
        for (int mt = 0; mt < 2; ++mt)
            #pragma unroll
            for (int r = 0; r < 4; ++r) {
                int t = mq*32 + mt*16 + lg*4 + r;
                float vt = *(const float*)(lds + R_UV + t*4) + cq;
                float m = -1e30f;
                #pragma unroll
                for (int nt = 0; nt < 4; ++nt) {
                    int s = nh*64 + nt*16 + lr;
                    float sv = sacc[mt][nt][r] + vt + uu[nt];
                    if (s > t) sv = -1e30f;
                    sacc[mt][nt][r] = sv;
                    m = fmaxf(m, sv);
                }
                m = fmaxf(m, __shfl_xor(m, 1));
                m = fmaxf(m, __shfl_xor(m, 2));
                m = fmaxf(m, __shfl_xor(m, 4));
                m = fmaxf(m, __shfl_xor(m, 8));
                rmax[mt][r] = m;
            }
        if (lr == 0) {
            #pragma unroll
            for (int mt = 0; mt < 2; ++mt)
                #pragma unroll
                for (int r = 0; r < 4; ++r)
                    redM[nh*128 + mq*32 + mt*16 + lg*4 + r] = rmax[mt][r];
        }
        LGKM0(); BAR();
        float rsum[2][4];
        #pragma unroll
        for (int mt = 0; mt < 2; ++mt)
            #pragma unroll
            for (int r = 0; r < 4; ++r) {
                int t = mq*32 + mt*16 + lg*4 + r;
                float m = fmaxf(redM[t], redM[128 + t]);
                float ssum = 0.f;
                #pragma unroll
                for (int nt = 0; nt < 4; ++nt) {
                    float p = __expf(sacc[mt][nt][r] - m);
                    sacc[mt][nt][r] = p;
                    ssum += p;
                }
                ssum += __shfl_xor(ssum, 1);
                ssum += __shfl_xor(ssum, 2);
                ssum += __shfl_xor(ssum, 4);
                ssum += __shfl_xor(ssum, 8);
                rsum[mt][r] = ssum;
            }
        if (lr == 0) {
            #pragma unroll
            for (int mt = 0; mt < 2; ++mt)
                #pragma unroll
                for (int r = 0; r < 4; ++r)
                    redS[nh*128 + mq*32 + mt*16 + lg*4 + r] = rsum[mt][r];
        }
        LGKM0(); BAR();
        #pragma unroll
        for (int mt = 0; mt < 2; ++mt)
            #pragma unroll
            for (int r = 0; r < 4; ++r) {
                int t = mq*32 + mt*16 + lg*4 + r;
                float inv = 1.0f / (redS[t] + redS[128 + t]);
                #pragma unroll
                for (int nt = 0; nt < 4; ++nt) {
                    int s = nh*64 + nt*16 + lr;
                    *(unsigned short*)(lds + R_P + t*256 + ((s*2) ^ ((t&7)<<4)))
                        = f2bf(sacc[mt][nt][r] * inv);
                }
            }
    }
    LGKM0(); BAR();

    // ---- Ph2: H = WM * X^T -> LDS [256e][256B swz] (over T1 region) ----
    #pragma unroll
    for (int p = 0; p < 2; ++p) {
        f32x4 acc[2][4];
        #pragma unroll
        for (int i = 0; i < 2; ++i)
            #pragma unroll
            for (int j = 0; j < 4; ++j) acc[i][j] = f32x4{0.f,0.f,0.f,0.f};
        #pragma unroll
        for (int ks = 0; ks < 8; ++ks) {
            short8 wa[2];
            #pragma unroll
            for (int me = 0; me < 2; ++me)
                wa[me] = *(const short8*)(WMh + (((w*2+me)*8 + ks) << 10) + l*16);
            short8 sb[4];
            #pragma unroll
            for (int nt = 0; nt < 4; ++nt)
                sb[nt] = *(const short8*)(Xf + (((p*4+nt)*8 + ks) << 10) + l*16);
            PRIO1();
            #pragma unroll
            for (int me = 0; me < 2; ++me)
                #pragma unroll
                for (int nt = 0; nt < 4; ++nt)
                    acc[me][nt] = __builtin_amdgcn_mfma_f32_16x16x32_bf16(wa[me], sb[nt], acc[me][nt], 0, 0, 0);
            PRIO0();
        }
        #pragma unroll
        for (int me = 0; me < 2; ++me)
            #pragma unroll
            for (int nt = 0; nt < 4; ++nt)
                #pragma unroll
                for (int r = 0; r < 4; ++r) {
                    int e = (w*2+me)*16 + lg*4 + r;
                    int s = (p*4+nt)*16 + lr;
                    *(unsigned short*)(lds + R_T1 + e*256 + ((s*2) ^ ((e&7)<<4)))
                        = f2bf(acc[me][nt][r]);
                }
    }
    LGKM0(); BAR();

    // ---- Ph3: OUT = P * H^T + bb ----
    const float* bbp = (const float*)(ws + WS_BB + h*1024);
    short8 pa[2][4];
    #pragma unroll
    for (int mt = 0; mt < 2; ++mt) {
        int t2 = mq*32 + mt*16 + lr;
        #pragma unroll
        for (int ks = 0; ks < 4; ++ks)
            pa[mt][ks] = *(const short8*)(lds + R_P + t2*256 + ((ks*64 + lg*16) ^ ((t2&7)<<4)));
    }
    #pragma unroll
    for (int ec = 0; ec < 4; ++ec) {
        f32x4 acc[2][2];
        #pragma unroll
        for (int i = 0; i < 2; ++i)
            #pragma unroll
            for (int j = 0; j < 2; ++j) acc[i][j] = f32x4{0.f,0.f,0.f,0.f};
        #pragma unroll
        for (int ks = 0; ks < 4; ++ks) {
            short8 hb[2];
            #pragma unroll
            for (int nt = 0; nt < 2; ++nt) {
                int er = (nh*8 + ec*2 + nt)*16 + lr;
                hb[nt] = *(const short8*)(lds + R_T1 + er*256 + ((ks*64 + lg*16) ^ ((er&7)<<4)));
            }
            PRIO1();
            #pragma unroll
            for (int mt = 0; mt < 2; ++mt)
                #pragma unroll
                for (int nt = 0; nt < 2; ++nt)
                    acc[mt][nt] = __builtin_amdgcn_mfma_f32_16x16x32_bf16(pa[mt][ks], hb[nt], acc[mt][nt], 0, 0, 0);
            PRIO0();
        }
        #pragma unroll
        for (int nt = 0; nt < 2; ++nt) {
            int e = (nh*8 + ec*2 + nt)*16 + lr;
            float bbv = bbp[e];
            #pragma unroll
            for (int mt = 0; mt < 2; ++mt)
                #pragma unroll
                for (int r = 0; r < 4; ++r) {
                    int t = mq*32 + mt*16 + lg*4 + r;
                    out[((size_t)bid * TT + t) * 256 + e] = acc[mt][nt][r] + bbv;
                }
        }
    }
}

extern "C" void kernel_launch(void* const* d_in, const int* in_sizes, int n_in,
                              void* d_out, int out_size, void* d_ws, size_t ws_size,
                              hipStream_t stream) {
    (void)in_sizes; (void)n_in; (void)out_size; (void)ws_size; // needs ws_size >= 18948128
    const float* x  = (const float*)d_in[0];
    const float* Wq = (const float*)d_in[1];
    const float* bq = (const float*)d_in[2];
    const float* Wk = (const float*)d_in[3];
    const float* bk = (const float*)d_in[4];
    const float* Wv = (const float*)d_in[5];
    const float* bv = (const float*)d_in[6];
    const float* Wp = (const float*)d_in[7];
    const float* bp = (const float*)d_in[8];
    char* ws = (char*)d_ws;

    hipFuncSetAttribute((const void*)convert_pre,
                        hipFuncAttributeMaxDynamicSharedMemorySize, 65536);
    convert_pre<<<dim3(513), dim3(256), 65536, stream>>>(
        x, Wq, bq, Wk, bk, Wv, bv, Wp, bp, ws);

    hipFuncSetAttribute((const void*)mha_fused,
                        hipFuncAttributeMaxDynamicSharedMemorySize, LDS_SIZE);
    mha_fused<<<dim3(2048), dim3(512), LDS_SIZE, stream>>>(ws, (float*)d_out);
}

// Round 9
// 281.938 us; speedup vs baseline: 2.1307x; 1.3806x over previous
//
#include <hip/hip_runtime.h>
#include <hip/hip_bf16.h>
#include <stdint.h>

// Fused causal MHA, B=256,T=128,H=8,D=256,C=256. One block per (h,b).
// Round 9: same mha_fused as round 8 (algebraic fold, 234us measured).
// convert_pre tail restructured: w1/w2/cqk = 8 per-head blocks with
// LDS-tiled coalesced staging; bb = 16 per-e-strip blocks with padded
// LDS Wp tiles + shfl reduce. Kills the serial single-block GEMVs.

#define TT 128

typedef __attribute__((ext_vector_type(8))) short short8;
typedef __attribute__((ext_vector_type(4))) float f32x4;

// ---- ws map (total 18948128 B < proven-available 20054016) ----
#define WS_X    0u                       // 256 b x 64KB  X A/B-frags
#define WS_M    16777216u                // 8 h x 128KB   M^T-layout B-frags (scaled 1/16)
#define WS_WM   17825792u                // 8 h x 128KB   WM A-frags
#define WS_WB   18874368u                // 8 h x 8KB     [w2;w1] B-frags (rows 0,1), zero-filled
#define WS_BB   18939904u                // 8 h x 1KB     bb fp32
#define WS_CQ   18948096u                // 8 x 4B        cqk fp32

// ---- LDS map (101376 B) ----
#define R_T1   0        // T1 [128t][512B swz] -> H [256e][256B swz]
#define R_P    65536    // P  [128t][256B swz]
#define R_UV   98304    // v[128] f32 | u[128] f32
#define R_RED  99328    // redM[256] | redS[256]
#define LDS_SIZE 101376

#define LGKM0()  asm volatile("s_waitcnt lgkmcnt(0)" ::: "memory")
#define BAR()    do { asm volatile("" ::: "memory"); __builtin_amdgcn_s_barrier(); asm volatile("" ::: "memory"); } while (0)
#define PRIO1()  __builtin_amdgcn_s_setprio(1)
#define PRIO0()  __builtin_amdgcn_s_setprio(0)

__device__ __forceinline__ unsigned short f2bf(float x) {
    union { float f; unsigned u; } v; v.f = x;
    unsigned r = v.u + 0x7FFFu + ((v.u >> 16) & 1u);
    return (unsigned short)(r >> 16);
}
__device__ __forceinline__ unsigned pk2(float a, float b) {
    return (unsigned)f2bf(a) | ((unsigned)f2bf(b) << 16);
}

// =============== convert / fold kernel =====================================
// blocks 0..255   : X[b] fp32 -> bf16 frag order (via LDS transpose)
// blocks 256..383 : M strips   (h = (bid-256)>>4, c'-strip = (bid-256)&15)
// blocks 384..511 : WM strips  (h = (bid-384)>>4, e-strip)
// blocks 512..519 : per-head w1/w2 frags + cqk (LDS-tiled, coalesced)
// blocks 520..535 : bb e-strips (LDS-tiled Wp + shfl reduce)
__global__ __launch_bounds__(256) void convert_pre(
    const float* __restrict__ x,
    const float* __restrict__ Wq, const float* __restrict__ bq,
    const float* __restrict__ Wk, const float* __restrict__ bk,
    const float* __restrict__ Wv, const float* __restrict__ bv,
    const float* __restrict__ Wp, const float* __restrict__ bp,
    char* __restrict__ ws)
{
    extern __shared__ char clds[];
    const int tid = threadIdx.x;
    const int bid = blockIdx.x;

    if (bid < 256) {
        // ---- X -> frag order ----
        const float* src = x + (size_t)bid * 32768;
        char* dst = ws + WS_X + (size_t)bid * 65536;
        for (int i = tid; i < 8192; i += 256) {
            float4 v = ((const float4*)src)[i];
            int row = i >> 6, c4 = i & 63;
            uint2 u; u.x = pk2(v.x, v.y); u.y = pk2(v.z, v.w);
            *(uint2*)(clds + row * 512 + ((c4 * 8) ^ ((row & 7) << 4))) = u;
        }
        __syncthreads();
        for (int i = tid; i < 4096; i += 256) {
            int l = i & 63, ks = (i >> 6) & 7, g = i >> 9;
            int r = g * 16 + (l & 15);
            int boff = ks * 64 + (l >> 4) * 16;
            uint4 q = *(const uint4*)(clds + r * 512 + (boff ^ ((r & 7) << 4)));
            ((uint4*)dst)[i] = q;
        }
        return;
    }
    if (bid < 384) {
        // ---- M[c,c'] = sum_d Wq[d,c] Wk[d,c'], store as B-frag of N[c',c]=M[c,c']/16 ----
        int id = bid - 256, h = id >> 4, st = id & 15;
        float* wkL = (float*)clds;                    // [256 d][16 cc]
        for (int i = tid; i < 4096; i += 256) {
            int d = i >> 4, cc = i & 15;
            wkL[i] = Wk[(size_t)h * 65536 + d * 256 + st * 16 + cc];
        }
        __syncthreads();
        const int c = tid;
        float acc[16];
        #pragma unroll
        for (int j = 0; j < 16; ++j) acc[j] = 0.f;
        #pragma unroll 4
        for (int d = 0; d < 256; ++d) {
            float a = Wq[(size_t)h * 65536 + d * 256 + c];
            #pragma unroll
            for (int j = 0; j < 16; ++j) acc[j] += a * wkL[d * 16 + j];
        }
        char* base = ws + WS_M + (size_t)h * 131072;
        int ks = c >> 5, lgp = (c >> 3) & 3, jb = c & 7;
        #pragma unroll
        for (int j = 0; j < 16; ++j) {
            int cp = st * 16 + j;                     // row (n) = c'
            *(unsigned short*)(base + (((st * 8 + ks)) << 10)
                + ((cp & 15) + 16 * lgp) * 16 + jb * 2) = f2bf(acc[j] * 0.0625f);
        }
        return;
    }
    if (bid < 512) {
        // ---- WM[e,c] = sum_d Wp[e,d] Wv_h[d,c], store as A-frag (row e, col c) ----
        int id = bid - 384, h = id >> 4, st = id & 15;
        float* wpL = (float*)clds;                    // [16 e][257 d]
        for (int i = tid; i < 4096; i += 256) {
            int e = i >> 8, d = i & 255;
            wpL[e * 257 + d] = Wp[(size_t)(st * 16 + e) * 256 + d];
        }
        __syncthreads();
        const int c = tid;
        float acc[16];
        #pragma unroll
        for (int j = 0; j < 16; ++j) acc[j] = 0.f;
        #pragma unroll 4
        for (int d = 0; d < 256; ++d) {
            float wv = Wv[(size_t)h * 65536 + d * 256 + c];
            #pragma unroll
            for (int j = 0; j < 16; ++j) acc[j] += wv * wpL[j * 257 + d];
        }
        char* base = ws + WS_WM + (size_t)h * 131072;
        int ks = c >> 5, lgp = (c >> 3) & 3, jb = c & 7;
        #pragma unroll
        for (int j = 0; j < 16; ++j) {
            *(unsigned short*)(base + (((st * 8 + ks)) << 10)
                + (j + 16 * lgp) * 16 + jb * 2) = f2bf(acc[j]);
        }
        return;
    }
    if (bid < 520) {
        // ---- per-head w1/w2 B-frags (rows 0=w2,1=w1) + cqk ----
        const int h = bid - 512;
        // zero this head's 8KB WB region
        {
            uint4 z = {0u,0u,0u,0u};
            for (int i = tid; i < 512; i += 256)
                ((uint4*)(ws + WS_WB + (size_t)h * 8192))[i] = z;
        }
        float* tK = (float*)clds;             // [16][256]
        float* tQ = (float*)(clds + 16384);   // [16][256]
        const int c = tid;
        float s1 = 0.f, s2 = 0.f;
        for (int d0 = 0; d0 < 256; d0 += 16) {
            __syncthreads();                  // also orders zero-fill before frag writes
            for (int i = tid; i < 1024; i += 256) {
                int row = i >> 6, c4 = i & 63;
                ((float4*)tK)[row * 64 + c4] =
                    ((const float4*)(Wk + (size_t)h * 65536 + (size_t)(d0 + row) * 256))[c4];
                ((float4*)tQ)[row * 64 + c4] =
                    ((const float4*)(Wq + (size_t)h * 65536 + (size_t)(d0 + row) * 256))[c4];
            }
            __syncthreads();
            #pragma unroll
            for (int dd = 0; dd < 16; ++dd) {
                s1 += tK[dd * 256 + c] * bq[h * 256 + d0 + dd];
                s2 += tQ[dd * 256 + c] * bk[h * 256 + d0 + dd];
            }
        }
        int ks = c >> 5, lgp = (c >> 3) & 3, jb = c & 7;
        char* base = ws + WS_WB + (size_t)h * 8192 + ks * 1024;
        *(unsigned short*)(base + (0 + 16 * lgp) * 16 + jb * 2) = f2bf(s2 * 0.0625f); // row0: w2
        *(unsigned short*)(base + (1 + 16 * lgp) * 16 + jb * 2) = f2bf(s1 * 0.0625f); // row1: w1
        // cqk
        float* red = (float*)(clds + 32768);
        red[tid] = bq[h * 256 + tid] * bk[h * 256 + tid];
        __syncthreads();
        if (tid == 0) {
            float cq = 0.f;
            for (int d = 0; d < 256; ++d) cq += red[d];
            *(float*)(ws + WS_CQ + h * 4) = cq * 0.0625f;
        }
        return;
    }
    {
        // ---- bb strips: bb[h][e] = bp[e] + sum_d bv[h][d] Wp[e][d] ----
        const int st = bid - 520;             // e-strip, e = st*16 + el
        float* wpT = (float*)clds;            // [16][257] padded
        float* bvL = (float*)(clds + 17408);  // [8][256]
        for (int i = tid; i < 1024; i += 256) {
            int row = i >> 6, c4 = i & 63;
            float4 v = ((const float4*)(Wp + (size_t)(st * 16 + row) * 256))[c4];
            float* dstp = wpT + row * 257 + c4 * 4;
            dstp[0] = v.x; dstp[1] = v.y; dstp[2] = v.z; dstp[3] = v.w;
        }
        for (int i = tid; i < 512; i += 256)
            ((float4*)bvL)[i] = ((const float4*)bv)[i];
        __syncthreads();
        const int el = tid >> 4, dg = tid & 15;
        #pragma unroll
        for (int h = 0; h < 8; ++h) {
            float p = 0.f;
            #pragma unroll
            for (int dd = 0; dd < 16; ++dd) {
                int d = dg * 16 + dd;
                p += bvL[h * 256 + d] * wpT[el * 257 + d];
            }
            p += __shfl_xor(p, 1);
            p += __shfl_xor(p, 2);
            p += __shfl_xor(p, 4);
            p += __shfl_xor(p, 8);
            if (dg == 0)
                *(float*)(ws + WS_BB + (size_t)h * 1024 + (st * 16 + el) * 4)
                    = bp[st * 16 + el] + p;
        }
        return;
    }
}

// =============== main fused kernel (unchanged from round 8) ================
__global__ __launch_bounds__(512, 2) void mha_fused(
    const char* __restrict__ ws, float* __restrict__ out)
{
    extern __shared__ char lds[];
    const int tid = threadIdx.x;
    const int w  = tid >> 6, l = tid & 63;
    const int lg = l >> 4, lr = l & 15;
    const int mq = w & 3, nh = w >> 2;      // 4 M-waves x 2 N-waves
    const int bid = blockIdx.x;
    const int h = bid >> 8, b = bid & 255;

    const char* Xf  = ws + WS_X  + (size_t)b * 65536;
    const char* Mh  = ws + WS_M  + (size_t)h * 131072;
    const char* WMh = ws + WS_WM + (size_t)h * 131072;
    const char* WBh = ws + WS_WB + (size_t)h * 8192;

    // X A-frags (row-groups mq*2+mt)
    short8 xf[2][8];
    #pragma unroll
    for (int mt = 0; mt < 2; ++mt)
        #pragma unroll
        for (int ks = 0; ks < 8; ++ks)
            xf[mt][ks] = *(const short8*)(Xf + (((mq*2 + mt)*8 + ks) << 10) + l*16);

    // ---- Ph0a: [v|u] = X * [w2;w1]^T ----
    {
        f32x4 vacc[2] = {f32x4{0.f,0.f,0.f,0.f}, f32x4{0.f,0.f,0.f,0.f}};
        #pragma unroll
        for (int ks = 0; ks < 8; ++ks) {
            short8 wb = *(const short8*)(WBh + (ks << 10) + l*16);
            vacc[0] = __builtin_amdgcn_mfma_f32_16x16x32_bf16(xf[0][ks], wb, vacc[0], 0, 0, 0);
            vacc[1] = __builtin_amdgcn_mfma_f32_16x16x32_bf16(xf[1][ks], wb, vacc[1], 0, 0, 0);
        }
        if (nh == 0 && lr < 2) {
            #pragma unroll
            for (int mt = 0; mt < 2; ++mt)
                #pragma unroll
                for (int r = 0; r < 4; ++r) {
                    int t = mq*32 + mt*16 + lg*4 + r;
                    *(float*)(lds + R_UV + lr*512 + t*4) = vacc[mt][r];
                }
        }
    }

    // ---- Ph0b: T1 = X * N  (N = M^T-layout, scaled 1/16) -> LDS C-layout ----
    #pragma unroll
    for (int p = 0; p < 2; ++p) {
        const int ga = nh*8 + p*4;
        f32x4 acc[2][4];
        #pragma unroll
        for (int i = 0; i < 2; ++i)
            #pragma unroll
            for (int j = 0; j < 4; ++j) acc[i][j] = f32x4{0.f,0.f,0.f,0.f};
        #pragma unroll
        for (int ks = 0; ks < 8; ++ks) {
            short8 nb[4];
            #pragma unroll
            for (int nt = 0; nt < 4; ++nt)
                nb[nt] = *(const short8*)(Mh + (((ga+nt)*8 + ks) << 10) + l*16);
            PRIO1();
            #pragma unroll
            for (int mt = 0; mt < 2; ++mt)
                #pragma unroll
                for (int nt = 0; nt < 4; ++nt)
                    acc[mt][nt] = __builtin_amdgcn_mfma_f32_16x16x32_bf16(xf[mt][ks], nb[nt], acc[mt][nt], 0, 0, 0);
            PRIO0();
        }
        #pragma unroll
        for (int mt = 0; mt < 2; ++mt)
            #pragma unroll
            for (int nt = 0; nt < 4; ++nt)
                #pragma unroll
                for (int r = 0; r < 4; ++r) {
                    int t = mq*32 + mt*16 + lg*4 + r;
                    int cp = (ga+nt)*16 + lr;
                    *(unsigned short*)(lds + R_T1 + t*512 + ((cp*2) ^ ((t&7)<<4)))
                        = f2bf(acc[mt][nt][r]);
                }
    }
    LGKM0(); BAR();

    // ---- Ph1: S = T1 * X^T + v + u + cqk ; mask ; softmax ; P -> LDS ----
    f32x4 sacc[2][4];
    #pragma unroll
    for (int i = 0; i < 2; ++i)
        #pragma unroll
        for (int j = 0; j < 4; ++j) sacc[i][j] = f32x4{0.f,0.f,0.f,0.f};
    #pragma unroll
    for (int ks = 0; ks < 8; ++ks) {
        short8 ta[2];
        #pragma unroll
        for (int mt = 0; mt < 2; ++mt) {
            int t2 = mq*32 + mt*16 + lr;
            ta[mt] = *(const short8*)(lds + R_T1 + t2*512 + ((ks*64 + lg*16) ^ ((t2&7)<<4)));
        }
        short8 sb[4];
        #pragma unroll
        for (int nt = 0; nt < 4; ++nt)
            sb[nt] = *(const short8*)(Xf + (((nh*4+nt)*8 + ks) << 10) + l*16);
        PRIO1();
        #pragma unroll
        for (int mt = 0; mt < 2; ++mt)
            #pragma unroll
            for (int nt = 0; nt < 4; ++nt)
                sacc[mt][nt] = __builtin_amdgcn_mfma_f32_16x16x32_bf16(ta[mt], sb[nt], sacc[mt][nt], 0, 0, 0);
        PRIO0();
    }
    {
        const float cq = *(const float*)(ws + WS_CQ + h*4);
        float uu[4];
        #pragma unroll
        for (int nt = 0; nt < 4; ++nt)
            uu[nt] = *(const float*)(lds + R_UV + 512 + (nh*64 + nt*16 + lr)*4);
        float* redM = (float*)(lds + R_RED);
        float* redS = redM + 256;
        float rmax[2][4];
        #pragma unroll
        for (int mt = 0; mt < 2; ++mt)
            #pragma unroll
            for (int r = 0; r < 4; ++r) {
                int t = mq*32 + mt*16 + lg*4 + r;
                float vt = *(const float*)(lds + R_UV + t*4) + cq;
                float m = -1e30f;
                #pragma unroll
                for (int nt = 0; nt < 4; ++nt) {
                    int s = nh*64 + nt*16 + lr;
                    float sv = sacc[mt][nt][r] + vt + uu[nt];
                    if (s > t) sv = -1e30f;
                    sacc[mt][nt][r] = sv;
                    m = fmaxf(m, sv);
                }
                m = fmaxf(m, __shfl_xor(m, 1));
                m = fmaxf(m, __shfl_xor(m, 2));
                m = fmaxf(m, __shfl_xor(m, 4));
                m = fmaxf(m, __shfl_xor(m, 8));
                rmax[mt][r] = m;
            }
        if (lr == 0) {
            #pragma unroll
            for (int mt = 0; mt < 2; ++mt)
                #pragma unroll
                for (int r = 0; r < 4; ++r)
                    redM[nh*128 + mq*32 + mt*16 + lg*4 + r] = rmax[mt][r];
        }
        LGKM0(); BAR();
        float rsum[2][4];
        #pragma unroll
        for (int mt = 0; mt < 2; ++mt)
            #pragma unroll
            for (int r = 0; r < 4; ++r) {
                int t = mq*32 + mt*16 + lg*4 + r;
                float m = fmaxf(redM[t], redM[128 + t]);
                float ssum = 0.f;
                #pragma unroll
                for (int nt = 0; nt < 4; ++nt) {
                    float p = __expf(sacc[mt][nt][r] - m);
                    sacc[mt][nt][r] = p;
                    ssum += p;
                }
                ssum += __shfl_xor(ssum, 1);
                ssum += __shfl_xor(ssum, 2);
                ssum += __shfl_xor(ssum, 4);
                ssum += __shfl_xor(ssum, 8);
                rsum[mt][r] = ssum;
            }
        if (lr == 0) {
            #pragma unroll
            for (int mt = 0; mt < 2; ++mt)
                #pragma unroll
                for (int r = 0; r < 4; ++r)
                    redS[nh*128 + mq*32 + mt*16 + lg*4 + r] = rsum[mt][r];
        }
        LGKM0(); BAR();
        #pragma unroll
        for (int mt = 0; mt < 2; ++mt)
            #pragma unroll
            for (int r = 0; r < 4; ++r) {
                int t = mq*32 + mt*16 + lg*4 + r;
                float inv = 1.0f / (redS[t] + redS[128 + t]);
                #pragma unroll
                for (int nt = 0; nt < 4; ++nt) {
                    int s = nh*64 + nt*16 + lr;
                    *(unsigned short*)(lds + R_P + t*256 + ((s*2) ^ ((t&7)<<4)))
                        = f2bf(sacc[mt][nt][r] * inv);
                }
            }
    }
    LGKM0(); BAR();

    // ---- Ph2: H = WM * X^T -> LDS [256e][256B swz] (over T1 region) ----
    #pragma unroll
    for (int p = 0; p < 2; ++p) {
        f32x4 acc[2][4];
        #pragma unroll
        for (int i = 0; i < 2; ++i)
            #pragma unroll
            for (int j = 0; j < 4; ++j) acc[i][j] = f32x4{0.f,0.f,0.f,0.f};
        #pragma unroll
        for (int ks = 0; ks < 8; ++ks) {
            short8 wa[2];
            #pragma unroll
            for (int me = 0; me < 2; ++me)
                wa[me] = *(const short8*)(WMh + (((w*2+me)*8 + ks) << 10) + l*16);
            short8 sb[4];
            #pragma unroll
            for (int nt = 0; nt < 4; ++nt)
                sb[nt] = *(const short8*)(Xf + (((p*4+nt)*8 + ks) << 10) + l*16);
            PRIO1();
            #pragma unroll
            for (int me = 0; me < 2; ++me)
                #pragma unroll
                for (int nt = 0; nt < 4; ++nt)
                    acc[me][nt] = __builtin_amdgcn_mfma_f32_16x16x32_bf16(wa[me], sb[nt], acc[me][nt], 0, 0, 0);
            PRIO0();
        }
        #pragma unroll
        for (int me = 0; me < 2; ++me)
            #pragma unroll
            for (int nt = 0; nt < 4; ++nt)
                #pragma unroll
                for (int r = 0; r < 4; ++r) {
                    int e = (w*2+me)*16 + lg*4 + r;
                    int s = (p*4+nt)*16 + lr;
                    *(unsigned short*)(lds + R_T1 + e*256 + ((s*2) ^ ((e&7)<<4)))
                        = f2bf(acc[me][nt][r]);
                }
    }
    LGKM0(); BAR();

    // ---- Ph3: OUT = P * H^T + bb ----
    const float* bbp = (const float*)(ws + WS_BB + h*1024);
    short8 pa[2][4];
    #pragma unroll
    for (int mt = 0; mt < 2; ++mt) {
        int t2 = mq*32 + mt*16 + lr;
        #pragma unroll
        for (int ks = 0; ks < 4; ++ks)
            pa[mt][ks] = *(const short8*)(lds + R_P + t2*256 + ((ks*64 + lg*16) ^ ((t2&7)<<4)));
    }
    #pragma unroll
    for (int ec = 0; ec < 4; ++ec) {
        f32x4 acc[2][2];
        #pragma unroll
        for (int i = 0; i < 2; ++i)
            #pragma unroll
            for (int j = 0; j < 2; ++j) acc[i][j] = f32x4{0.f,0.f,0.f,0.f};
        #pragma unroll
        for (int ks = 0; ks < 4; ++ks) {
            short8 hb[2];
            #pragma unroll
            for (int nt = 0; nt < 2; ++nt) {
                int er = (nh*8 + ec*2 + nt)*16 + lr;
                hb[nt] = *(const short8*)(lds + R_T1 + er*256 + ((ks*64 + lg*16) ^ ((er&7)<<4)));
            }
            PRIO1();
            #pragma unroll
            for (int mt = 0; mt < 2; ++mt)
                #pragma unroll
                for (int nt = 0; nt < 2; ++nt)
                    acc[mt][nt] = __builtin_amdgcn_mfma_f32_16x16x32_bf16(pa[mt][ks], hb[nt], acc[mt][nt], 0, 0, 0);
            PRIO0();
        }
        #pragma unroll
        for (int nt = 0; nt < 2; ++nt) {
            int e = (nh*8 + ec*2 + nt)*16 + lr;
            float bbv = bbp[e];
            #pragma unroll
            for (int mt = 0; mt < 2; ++mt)
                #pragma unroll
                for (int r = 0; r < 4; ++r) {
                    int t = mq*32 + mt*16 + lg*4 + r;
                    out[((size_t)bid * TT + t) * 256 + e] = acc[mt][nt][r] + bbv;
                }
        }
    }
}

extern "C" void kernel_launch(void* const* d_in, const int* in_sizes, int n_in,
                              void* d_out, int out_size, void* d_ws, size_t ws_size,
                              hipStream_t stream) {
    (void)in_sizes; (void)n_in; (void)out_size; (void)ws_size; // needs ws_size >= 18948128
    const float* x  = (const float*)d_in[0];
    const float* Wq = (const float*)d_in[1];
    const float* bq = (const float*)d_in[2];
    const float* Wk = (const float*)d_in[3];
    const float* bk = (const float*)d_in[4];
    const float* Wv = (const float*)d_in[5];
    const float* bv = (const float*)d_in[6];
    const float* Wp = (const float*)d_in[7];
    const float* bp = (const float*)d_in[8];
    char* ws = (char*)d_ws;

    hipFuncSetAttribute((const void*)convert_pre,
                        hipFuncAttributeMaxDynamicSharedMemorySize, 65536);
    convert_pre<<<dim3(536), dim3(256), 65536, stream>>>(
        x, Wq, bq, Wk, bk, Wv, bv, Wp, bp, ws);

    hipFuncSetAttribute((const void*)mha_fused,
                        hipFuncAttributeMaxDynamicSharedMemorySize, LDS_SIZE);
    mha_fused<<<dim3(2048), dim3(512), LDS_SIZE, stream>>>(ws, (float*)d_out);
}